// Round 6
// baseline (5708.924 us; speedup 1.0000x reference)
//
#include <hip/hip_runtime.h>
#include <hip/hip_bf16.h>
#include <stdint.h>

typedef unsigned short u16;
typedef __attribute__((ext_vector_type(8))) __bf16 bf16x8;
typedef __attribute__((ext_vector_type(16))) float f32x16;

#define BATCH 8192
#define HID   2048
#define COMB  4096
#define NTT   128   // K tiles of 32

__device__ __forceinline__ u16 f2bf(float f) {
  uint32_t u = __float_as_uint(f);
  u += 0x7fffu + ((u >> 16) & 1u);
  return (u16)(u >> 16);
}
__device__ __forceinline__ float bf2f(u16 b) {
  return __uint_as_float(((uint32_t)b) << 16);
}
__device__ __forceinline__ float fsigmoid(float x) { return 1.0f / (1.0f + __expf(-x)); }
__device__ __forceinline__ float ftanh(float x) { return 1.0f - 2.0f / (__expf(2.0f * x) + 1.0f); }

__device__ __forceinline__ void gload_lds16(const void* g, void* l) {
  __builtin_amdgcn_global_load_lds(
      (__attribute__((address_space(1))) void*)(uintptr_t)g,
      (__attribute__((address_space(3))) void*)(uintptr_t)l,
      16, 0, 0);
}

#define VM0() asm volatile("s_waitcnt vmcnt(0)" ::: "memory")

// ---- pack [x | h_prev] f32 -> A1 bf16 [8192][4096] ----
__global__ void pack_A_kernel(const float* __restrict__ x, const float* __restrict__ h,
                              u16* __restrict__ A1) {
  const size_t tid = (size_t)blockIdx.x * blockDim.x + threadIdx.x;
  const int r  = (int)(tid >> 9);
  const int c8 = (int)(tid & 511);
  const float* s = (c8 < 256) ? (x + (size_t)r * 2048 + (size_t)c8 * 8)
                              : (h + (size_t)r * 2048 + (size_t)(c8 - 256) * 8);
  const float4 v0 = ((const float4*)s)[0];
  const float4 v1 = ((const float4*)s)[1];
  const uint32_t p0 = (uint32_t)f2bf(v0.x) | ((uint32_t)f2bf(v0.y) << 16);
  const uint32_t p1 = (uint32_t)f2bf(v0.z) | ((uint32_t)f2bf(v0.w) << 16);
  const uint32_t p2 = (uint32_t)f2bf(v1.x) | ((uint32_t)f2bf(v1.y) << 16);
  const uint32_t p3 = (uint32_t)f2bf(v1.z) | ((uint32_t)f2bf(v1.w) << 16);
  *(uint4*)(A1 + tid * 8) = make_uint4(p0, p1, p2, p3);
}

// ---- transpose W [4096][2048] f32 -> dst [2048][4096] bf16 ----
__global__ void transpose_w_kernel(const float* __restrict__ src, u16* __restrict__ dst) {
  __shared__ float tile[32][33];
  const int n0 = blockIdx.x * 32;
  const int k0 = blockIdx.y * 32;
  const int tx = threadIdx.x, ty = threadIdx.y;
#pragma unroll
  for (int i = 0; i < 32; i += 8)
    tile[ty + i][tx] = src[(size_t)(k0 + ty + i) * 2048 + n0 + tx];
  __syncthreads();
#pragma unroll
  for (int i = 0; i < 32; i += 8)
    dst[(size_t)(n0 + ty + i) * 4096 + k0 + tx] = f2bf(tile[tx][ty + i]);
}

// ---- 256x256x32 double-buffered GEMM, 32x32x16 MFMA, 2 blocks/CU ----
// LDS 64KB: A slots 16KB @0,16K ; B slots 16KB @32K,48K
template <int MODE>
__global__ __launch_bounds__(512, 4) void gemm32_kernel(
    const u16* __restrict__ A1, const u16* __restrict__ RH,
    const u16* __restrict__ Bt, const float* __restrict__ h_prev,
    const float* __restrict__ bias0, const float* __restrict__ bias1,
    u16* __restrict__ Z, u16* __restrict__ RHout, float* __restrict__ out) {
  extern __shared__ char smem[];
  constexpr int NBN = (MODE == 0) ? 16 : 8;

  const int t = threadIdx.x;
  const int l = t & 63, w = t >> 6;
  const int wm = w >> 2, wn = w & 3;   // 2M x 4N waves; wave tile 128x64
  const int l31 = l & 31;
  const int kb  = l >> 5;              // k-half within fragment

  const int nwg = 32 * NBN;
  int bid = blockIdx.x;
  bid = (bid & 7) * (nwg >> 3) + (bid >> 3);
  const int bm = bid / NBN, bn = bid % NBN;
  const int arow = bm * 256;
  const int brow = bn * 256;

  // staging: wave w, gload i covers rows w*32+i*16 + (l>>2), 16B granule (l&3)
  // swizzle: LDS(row, g) = global(row, g ^ (row&3)); row&3 == (l>>2)&3
  const int srow = l >> 2;                  // 0..15
  const int sg   = (l & 3) ^ (srow & 3);    // swizzled source granule

  auto stageA = [&](int T, char* slot) {
    const u16* src;
    size_t ld;
    int koff;
    if constexpr (MODE == 1) {
      if (T >= 64) { src = RH; ld = HID;  koff = T * 32 - 2048; }
      else         { src = A1; ld = COMB; koff = T * 32; }
    } else {
      src = A1; ld = COMB; koff = T * 32;
    }
#pragma unroll
    for (int i = 0; i < 2; ++i) {
      const int r0 = w * 32 + i * 16;
      gload_lds16(src + (size_t)(arow + r0 + srow) * ld + koff + sg * 8, slot + r0 * 64);
    }
  };
  auto stageB = [&](int T, char* slot) {
#pragma unroll
    for (int i = 0; i < 2; ++i) {
      const int r0 = w * 32 + i * 16;
      gload_lds16(Bt + (size_t)(brow + r0 + srow) * COMB + T * 32 + sg * 8, slot + r0 * 64);
    }
  };

  // lane-constant swizzled read offsets: row=32t+l31, k-gran = ks*2+kb
  // byte = row*64 + ((gran ^ (row&3))<<4); row&3 == l&3
  const int loff0 = l31 * 64 + (((0 * 2 + kb) ^ (l & 3)) << 4);
  const int loff1 = l31 * 64 + (((1 * 2 + kb) ^ (l & 3)) << 4);

  char* As0 = smem;          char* As1 = smem + 16384;
  char* Bs0 = smem + 32768;  char* Bs1 = smem + 49152;

  stageA(0, As0); stageB(0, Bs0);
  VM0();
  __builtin_amdgcn_s_barrier();

  f32x16 acc[4][2] = {};

#pragma unroll 2
  for (int j = 0; j < NTT; ++j) {
    char* As = (j & 1) ? As1 : As0;
    char* Bs = (j & 1) ? Bs1 : Bs0;
    char* An = (j & 1) ? As0 : As1;
    char* Bn = (j & 1) ? Bs0 : Bs1;

    if (j + 1 < NTT) { stageA(j + 1, An); stageB(j + 1, Bn); }

    bf16x8 af[4][2], bb[2][2];
#pragma unroll
    for (int mt = 0; mt < 4; ++mt) {
      af[mt][0] = *(const bf16x8*)(As + wm * 8192 + mt * 2048 + loff0);
      af[mt][1] = *(const bf16x8*)(As + wm * 8192 + mt * 2048 + loff1);
    }
#pragma unroll
    for (int nt = 0; nt < 2; ++nt) {
      bb[nt][0] = *(const bf16x8*)(Bs + wn * 4096 + nt * 2048 + loff0);
      bb[nt][1] = *(const bf16x8*)(Bs + wn * 4096 + nt * 2048 + loff1);
    }

#pragma unroll
    for (int mt = 0; mt < 4; ++mt)
#pragma unroll
      for (int nt = 0; nt < 2; ++nt)
#pragma unroll
        for (int ks = 0; ks < 2; ++ks)
          acc[mt][nt] = __builtin_amdgcn_mfma_f32_32x32x16_bf16(
              af[mt][ks], bb[nt][ks], acc[mt][nt], 0, 0, 0);

    if (j + 1 < NTT) VM0();
    __builtin_amdgcn_s_barrier();
  }

  // ---- epilogue: C row = arow + wm*128 + mt*32 + (e&3)+8*(e>>2)+4*kb, col = brow + wn*64 + nt*32 + l31
  const int r0g = arow + wm * 128 + kb * 4;
  const int c0g = brow + wn * 64 + l31;
  if constexpr (MODE == 0) {
    const bool isZ = (bn < 8);
    const float* bias = isZ ? bias0 : bias1;
#pragma unroll
    for (int nt = 0; nt < 2; ++nt) {
      const int colg = c0g + nt * 32;
      const int col = isZ ? colg : (colg - 2048);
      const float bv = bias[col];
#pragma unroll
      for (int mt = 0; mt < 4; ++mt)
#pragma unroll
        for (int e = 0; e < 16; ++e) {
          const int row = r0g + mt * 32 + (e & 3) + 8 * (e >> 2);
          const size_t idx = (size_t)row * HID + col;
          const float v = acc[mt][nt][e] + bv;
          if (isZ) {
            Z[idx] = f2bf(fsigmoid(v));
          } else {
            const float rv = fsigmoid(v);
            RHout[idx] = f2bf(rv * h_prev[idx]);
          }
        }
    }
  } else {
#pragma unroll
    for (int nt = 0; nt < 2; ++nt) {
      const int col = c0g + nt * 32;
      const float bv = bias0[col];
#pragma unroll
      for (int mt = 0; mt < 4; ++mt)
#pragma unroll
        for (int e = 0; e < 16; ++e) {
          const int row = r0g + mt * 32 + (e & 3) + 8 * (e >> 2);
          const size_t idx = (size_t)row * HID + col;
          const float nn = ftanh(acc[mt][nt][e] + bv);
          const float zz = bf2f(Z[idx]);
          const float hp = h_prev[idx];
          out[idx] = (1.0f - zz) * hp + zz * nn;
        }
    }
  }
}

extern "C" void kernel_launch(void* const* d_in, const int* in_sizes, int n_in,
                              void* d_out, int out_size, void* d_ws, size_t ws_size,
                              hipStream_t stream) {
  const float* x  = (const float*)d_in[0];
  const float* h  = (const float*)d_in[1];
  const float* Wz = (const float*)d_in[2];
  const float* bz = (const float*)d_in[3];
  const float* Wr = (const float*)d_in[4];
  const float* br = (const float*)d_in[5];
  const float* Wn = (const float*)d_in[6];
  const float* bn = (const float*)d_in[7];
  float* out = (float*)d_out;

  char* ws = (char*)d_ws;
  u16* A1  = (u16*)(ws);                    // 8192*4096*2 = 67108864
  u16* RH  = (u16*)(ws + 67108864);         // 8192*2048*2 = 33554432
  u16* B1t = (u16*)(ws + 100663296);        // 4096*4096*2 = 33554432  ([Wz;Wr]^T)
  u16* B2t = (u16*)(ws + 134217728);        // 2048*4096*2 = 16777216  (Wn^T)
  u16* Z   = (u16*)(ws + 150994944);        // 8192*2048*2 = 33554432

  (void)hipFuncSetAttribute(reinterpret_cast<const void*>(&gemm32_kernel<0>),
                            hipFuncAttributeMaxDynamicSharedMemorySize, 65536);
  (void)hipFuncSetAttribute(reinterpret_cast<const void*>(&gemm32_kernel<1>),
                            hipFuncAttributeMaxDynamicSharedMemorySize, 65536);

  pack_A_kernel<<<16384, 256, 0, stream>>>(x, h, A1);
  dim3 tb(32, 8);
  transpose_w_kernel<<<dim3(64, 128), tb, 0, stream>>>(Wz, B1t);
  transpose_w_kernel<<<dim3(64, 128), tb, 0, stream>>>(Wr, B1t + (size_t)2048 * 4096);
  transpose_w_kernel<<<dim3(64, 128), tb, 0, stream>>>(Wn, B2t);

  gemm32_kernel<0><<<dim3(512), 512, 65536, stream>>>(A1, nullptr, B1t, h, bz, br, Z, RH, nullptr);
  gemm32_kernel<1><<<dim3(256), 512, 65536, stream>>>(A1, RH, B2t, h, bn, nullptr, Z, nullptr, out);
}

// Round 7
// 1541.347 us; speedup vs baseline: 3.7039x; 3.7039x over previous
//
#include <hip/hip_runtime.h>
#include <hip/hip_bf16.h>
#include <stdint.h>

typedef unsigned short u16;
typedef __attribute__((ext_vector_type(8))) __bf16 bf16x8;
typedef __attribute__((ext_vector_type(16))) float f32x16;

#define BATCH 8192
#define HID   2048
#define COMB  4096
#define NTT   128   // K tiles of 32

__device__ __forceinline__ u16 f2bf(float f) {
  uint32_t u = __float_as_uint(f);
  u += 0x7fffu + ((u >> 16) & 1u);
  return (u16)(u >> 16);
}
__device__ __forceinline__ float bf2f(u16 b) {
  return __uint_as_float(((uint32_t)b) << 16);
}
__device__ __forceinline__ float fsigmoid(float x) { return 1.0f / (1.0f + __expf(-x)); }
__device__ __forceinline__ float ftanh(float x) { return 1.0f - 2.0f / (__expf(2.0f * x) + 1.0f); }

__device__ __forceinline__ void gload_lds16(const void* g, void* l) {
  __builtin_amdgcn_global_load_lds(
      (__attribute__((address_space(1))) void*)(uintptr_t)g,
      (__attribute__((address_space(3))) void*)(uintptr_t)l,
      16, 0, 0);
}

#define BARRIER() do { asm volatile("" ::: "memory"); __builtin_amdgcn_s_barrier(); asm volatile("" ::: "memory"); } while (0)
#define VM8() asm volatile("s_waitcnt vmcnt(8)" ::: "memory")
#define VM0() asm volatile("s_waitcnt vmcnt(0)" ::: "memory")

// ---- pack [x | h_prev] f32 -> A1 bf16 [8192][4096] ----
__global__ void pack_A_kernel(const float* __restrict__ x, const float* __restrict__ h,
                              u16* __restrict__ A1) {
  const size_t tid = (size_t)blockIdx.x * blockDim.x + threadIdx.x;
  const int r  = (int)(tid >> 9);
  const int c8 = (int)(tid & 511);
  const float* s = (c8 < 256) ? (x + (size_t)r * 2048 + (size_t)c8 * 8)
                              : (h + (size_t)r * 2048 + (size_t)(c8 - 256) * 8);
  const float4 v0 = ((const float4*)s)[0];
  const float4 v1 = ((const float4*)s)[1];
  const uint32_t p0 = (uint32_t)f2bf(v0.x) | ((uint32_t)f2bf(v0.y) << 16);
  const uint32_t p1 = (uint32_t)f2bf(v0.z) | ((uint32_t)f2bf(v0.w) << 16);
  const uint32_t p2 = (uint32_t)f2bf(v1.x) | ((uint32_t)f2bf(v1.y) << 16);
  const uint32_t p3 = (uint32_t)f2bf(v1.z) | ((uint32_t)f2bf(v1.w) << 16);
  *(uint4*)(A1 + tid * 8) = make_uint4(p0, p1, p2, p3);
}

// ---- transpose W [4096][2048] f32 -> dst [2048][4096] bf16 ----
__global__ void transpose_w_kernel(const float* __restrict__ src, u16* __restrict__ dst) {
  __shared__ float tile[32][33];
  const int n0 = blockIdx.x * 32;
  const int k0 = blockIdx.y * 32;
  const int tx = threadIdx.x, ty = threadIdx.y;
#pragma unroll
  for (int i = 0; i < 32; i += 8)
    tile[ty + i][tx] = src[(size_t)(k0 + ty + i) * 2048 + n0 + tx];
  __syncthreads();
#pragma unroll
  for (int i = 0; i < 32; i += 8)
    dst[(size_t)(n0 + ty + i) * 4096 + k0 + tx] = f2bf(tile[tx][ty + i]);
}

// ---- 256x256x32 GEMM, 4 waves, wave-tile 128x128, 32x32x16 MFMA, triple-buffer ----
// LDS 96KB: A slots 16KB @0,16K,32K ; B slots 16KB @48K,64K,80K
template <int MODE>
__global__ __launch_bounds__(256, 1) void gemmbt_kernel(
    const u16* __restrict__ A1, const u16* __restrict__ RH,
    const u16* __restrict__ Bt, const float* __restrict__ h_prev,
    const float* __restrict__ bias0, const float* __restrict__ bias1,
    u16* __restrict__ Z, u16* __restrict__ RHout, float* __restrict__ out) {
  extern __shared__ char smem[];
  constexpr int NBN = (MODE == 0) ? 16 : 8;

  const int t = threadIdx.x;
  const int l = t & 63, w = t >> 6;        // 4 waves
  const int wm = w >> 1, wn = w & 1;       // 2M x 2N; wave tile 128x128
  const int l31 = l & 31;
  const int kb  = l >> 5;                  // k-half within fragment

  const int nwg = 32 * NBN;
  int bid = blockIdx.x;
  bid = (bid & 7) * (nwg >> 3) + (bid >> 3);
  const int bm = bid / NBN, bn = bid % NBN;
  const int arow = bm * 256;
  const int brow = bn * 256;

  // staging: gload i covers 16 rows (4 lanes/row, 4 granules of 16B = 64B = BK)
  // swizzle: LDS(row, g) = global(row, g ^ ((row>>1)&3))   [R5-verified, 0 conflicts]
  const int srow = l >> 2;                       // 0..15
  const int sg   = (l & 3) ^ ((srow >> 1) & 3);  // swizzled source granule

  auto stageA = [&](int T, char* slot) {
    const u16* src;
    size_t ld;
    int koff;
    if constexpr (MODE == 1) {
      if (T >= 64) { src = RH; ld = HID;  koff = T * 32 - 2048; }
      else         { src = A1; ld = COMB; koff = T * 32; }
    } else {
      src = A1; ld = COMB; koff = T * 32;
    }
#pragma unroll
    for (int i = 0; i < 4; ++i) {
      const int r0 = w * 64 + i * 16;
      gload_lds16(src + (size_t)(arow + r0 + srow) * ld + koff + sg * 8, slot + r0 * 64);
    }
  };
  auto stageB = [&](int T, char* slot) {
#pragma unroll
    for (int i = 0; i < 4; ++i) {
      const int r0 = w * 64 + i * 16;
      gload_lds16(Bt + (size_t)(brow + r0 + srow) * COMB + T * 32 + sg * 8, slot + r0 * 64);
    }
  };

  // lane-constant swizzled read offsets: row = 32-mult + l31, k-gran = ks*2+kb
  // byte = row*64 + ((gran ^ ((row>>1)&3))<<4)
  const int loff0 = l31 * 64 + (((0 + kb) ^ ((l31 >> 1) & 3)) << 4);
  const int loff1 = l31 * 64 + (((2 + kb) ^ ((l31 >> 1) & 3)) << 4);

  char* As0 = smem;          char* As1 = smem + 16384;  char* As2 = smem + 32768;
  char* Bs0 = smem + 49152;  char* Bs1 = smem + 65536;  char* Bs2 = smem + 81920;

  // Prologue: stage tiles 0,1; wait own tile-0 loads (8), barrier certifies all waves.
  stageA(0, As0); stageB(0, Bs0);
  stageA(1, As1); stageB(1, Bs1);
  VM8();
  BARRIER();

  f32x16 acc[4][4] = {};

  for (int j = 0; j < NTT; ++j) {
    if (j < NTT - 2) { stageA(j + 2, As2); stageB(j + 2, Bs2); }

    bf16x8 af[4][2], bb[4][2];
#pragma unroll
    for (int mt = 0; mt < 4; ++mt) {
      const char* p = As0 + (wm * 128 + mt * 32) * 64;
      af[mt][0] = *(const bf16x8*)(p + loff0);
      af[mt][1] = *(const bf16x8*)(p + loff1);
    }
#pragma unroll
    for (int nt = 0; nt < 4; ++nt) {
      const char* p = Bs0 + (wn * 128 + nt * 32) * 64;
      bb[nt][0] = *(const bf16x8*)(p + loff0);
      bb[nt][1] = *(const bf16x8*)(p + loff1);
    }

#pragma unroll
    for (int ks = 0; ks < 2; ++ks)
#pragma unroll
      for (int mt = 0; mt < 4; ++mt)
#pragma unroll
        for (int nt = 0; nt < 4; ++nt)
          acc[mt][nt] = __builtin_amdgcn_mfma_f32_32x32x16_bf16(
              af[mt][ks], bb[nt][ks], acc[mt][nt], 0, 0, 0);

    if (j < NTT - 2) { VM8(); } else if (j == NTT - 2) { VM0(); }
    if (j < NTT - 1) BARRIER();

    char* ta = As0; As0 = As1; As1 = As2; As2 = ta;
    char* tb = Bs0; Bs0 = Bs1; Bs1 = Bs2; Bs2 = tb;
  }

  // ---- epilogue: row = arow + wm*128 + mt*32 + (e&3)+8*(e>>2)+4*kb ; col = brow + wn*128 + nt*32 + l31
  const int r0g = arow + wm * 128 + kb * 4;
  const int c0g = brow + wn * 128 + l31;
  if constexpr (MODE == 0) {
    const bool isZ = (bn < 8);
    const float* bias = isZ ? bias0 : bias1;
#pragma unroll
    for (int nt = 0; nt < 4; ++nt) {
      const int colg = c0g + nt * 32;
      const int col = isZ ? colg : (colg - 2048);
      const float bv = bias[col];
#pragma unroll
      for (int mt = 0; mt < 4; ++mt)
#pragma unroll
        for (int e = 0; e < 16; ++e) {
          const int row = r0g + mt * 32 + (e & 3) + 8 * (e >> 2);
          const size_t idx = (size_t)row * HID + col;
          const float v = acc[mt][nt][e] + bv;
          if (isZ) {
            Z[idx] = f2bf(fsigmoid(v));
          } else {
            const float rv = fsigmoid(v);
            RHout[idx] = f2bf(rv * h_prev[idx]);
          }
        }
    }
  } else {
#pragma unroll
    for (int nt = 0; nt < 4; ++nt) {
      const int col = c0g + nt * 32;
      const float bv = bias0[col];
#pragma unroll
      for (int mt = 0; mt < 4; ++mt)
#pragma unroll
        for (int e = 0; e < 16; ++e) {
          const int row = r0g + mt * 32 + (e & 3) + 8 * (e >> 2);
          const size_t idx = (size_t)row * HID + col;
          const float nn = ftanh(acc[mt][nt][e] + bv);
          const float zz = bf2f(Z[idx]);
          const float hp = h_prev[idx];
          out[idx] = (1.0f - zz) * hp + zz * nn;
        }
    }
  }
}

extern "C" void kernel_launch(void* const* d_in, const int* in_sizes, int n_in,
                              void* d_out, int out_size, void* d_ws, size_t ws_size,
                              hipStream_t stream) {
  const float* x  = (const float*)d_in[0];
  const float* h  = (const float*)d_in[1];
  const float* Wz = (const float*)d_in[2];
  const float* bz = (const float*)d_in[3];
  const float* Wr = (const float*)d_in[4];
  const float* br = (const float*)d_in[5];
  const float* Wn = (const float*)d_in[6];
  const float* bn = (const float*)d_in[7];
  float* out = (float*)d_out;

  char* ws = (char*)d_ws;
  u16* A1  = (u16*)(ws);                    // 8192*4096*2 = 67108864
  u16* RH  = (u16*)(ws + 67108864);         // 8192*2048*2 = 33554432
  u16* B1t = (u16*)(ws + 100663296);        // 4096*4096*2 = 33554432  ([Wz;Wr]^T)
  u16* B2t = (u16*)(ws + 134217728);        // 2048*4096*2 = 16777216  (Wn^T)
  u16* Z   = (u16*)(ws + 150994944);        // 8192*2048*2 = 33554432

  (void)hipFuncSetAttribute(reinterpret_cast<const void*>(&gemmbt_kernel<0>),
                            hipFuncAttributeMaxDynamicSharedMemorySize, 98304);
  (void)hipFuncSetAttribute(reinterpret_cast<const void*>(&gemmbt_kernel<1>),
                            hipFuncAttributeMaxDynamicSharedMemorySize, 98304);

  pack_A_kernel<<<16384, 256, 0, stream>>>(x, h, A1);
  dim3 tb(32, 8);
  transpose_w_kernel<<<dim3(64, 128), tb, 0, stream>>>(Wz, B1t);
  transpose_w_kernel<<<dim3(64, 128), tb, 0, stream>>>(Wr, B1t + (size_t)2048 * 4096);
  transpose_w_kernel<<<dim3(64, 128), tb, 0, stream>>>(Wn, B2t);

  gemmbt_kernel<0><<<dim3(512), 256, 98304, stream>>>(A1, nullptr, B1t, h, bz, br, Z, RH, nullptr);
  gemmbt_kernel<1><<<dim3(256), 256, 98304, stream>>>(A1, RH, B2t, h, bn, nullptr, Z, nullptr, out);
}